// Round 21
// baseline (2232.712 us; speedup 1.0000x reference)
//
#include <hip/hip_runtime.h>
#include <hip/hip_bf16.h>
#include <math.h>

#define VOCAB 50257
#define CTX 2048
#define DMODEL 1024
#define NHEAD 16
#define NLAYER 8
#define DHEAD 64
#define BATCH 2
#define SEQ 2048
#define NTOK (BATCH * SEQ)   // 4096

typedef __bf16 bf16x8 __attribute__((ext_vector_type(8)));
typedef float  f32x4  __attribute__((ext_vector_type(4)));
typedef unsigned short ushort4v __attribute__((ext_vector_type(4)));
typedef unsigned short ushort8v __attribute__((ext_vector_type(8)));

__device__ inline void gl_lds16(const void* g, void* l) {
    __builtin_amdgcn_global_load_lds(
        (const __attribute__((address_space(1))) unsigned int*)g,
        (__attribute__((address_space(3))) unsigned int*)l, 16, 0, 0);
}

__device__ inline unsigned short f2bs(float v) {
    __hip_bfloat16 t = __float2bfloat16(v);
    return *(unsigned short*)&t;
}
__device__ inline float bs2f(unsigned short u) {
    return __uint_as_float(((unsigned)u) << 16);
}

// ---------------- embedding body: h (bf16) = wte[x] + wpe[pos] ----------------
__device__ void embed_body(int t, const int* __restrict__ x,
                           const float* __restrict__ wte,
                           const float* __restrict__ wpe,
                           unsigned short* __restrict__ h) {
    int s = t & (SEQ - 1);
    int tok = x[t];
    const float* pe = wpe + (long)s * DMODEL;
    const float* te = wte + (long)tok * DMODEL;
    unsigned short* ph = h + (long)t * DMODEL;
    int d = threadIdx.x * 4;
    f32x4 t4 = *(const f32x4*)&te[d];
    f32x4 p4 = *(const f32x4*)&pe[d];
    ushort4v o;
    #pragma unroll
    for (int j = 0; j < 4; ++j) o[j] = f2bs(t4[j] + p4[j]);
    *(ushort4v*)&ph[d] = o;
}

// ---------------- layernorm ----------------
__device__ inline float wave_sum(float v) {
    for (int off = 32; off; off >>= 1) v += __shfl_xor(v, off);
    return v;
}

// wave-per-row LN, bf16 in -> bf16 out
__global__ void ln_wave(const unsigned short* __restrict__ in,
                        unsigned short* __restrict__ out,
                        const float* __restrict__ g, const float* __restrict__ b) {
    const int w = threadIdx.x >> 6, lane = threadIdx.x & 63;
    const int row = blockIdx.x * 4 + w;
    const unsigned short* px = in + (long)row * DMODEL;
    ushort8v u[2];
    u[0] = *(const ushort8v*)&px[lane * 16];
    u[1] = *(const ushort8v*)&px[lane * 16 + 8];
    float x[16];
    float s = 0.f;
    #pragma unroll
    for (int i = 0; i < 16; ++i) { x[i] = bs2f(u[i >> 3][i & 7]); s += x[i]; }
    s = wave_sum(s);
    const float mean = s * (1.0f / DMODEL);
    float s2 = 0.f;
    #pragma unroll
    for (int i = 0; i < 16; ++i) { float d = x[i] - mean; s2 += d * d; }
    s2 = wave_sum(s2);
    const float r = 1.0f / sqrtf(s2 * (1.0f / DMODEL) + 1e-5f);
    unsigned short* po = out + (long)row * DMODEL;
    const int d0 = lane * 16;
    #pragma unroll
    for (int p = 0; p < 2; ++p) {
        ushort8v pk;
        #pragma unroll
        for (int j = 0; j < 8; ++j) {
            int d = d0 + p * 8 + j;
            pk[j] = f2bs((x[p * 8 + j] - mean) * r * g[d] + b[d]);
        }
        *(ushort8v*)&po[d0 + p * 8] = pk;
    }
}

// final LN: bf16 in -> f32 out (2 rows)
__global__ void ln_final(const unsigned short* __restrict__ in, float* __restrict__ out,
                         const float* __restrict__ g, const float* __restrict__ b,
                         long row_stride) {
    __shared__ float red[4], red2[4];
    int row = blockIdx.x;
    const unsigned short* px = in + (long)row * row_stride;
    float* po = out + (long)row * DMODEL;
    int tid = threadIdx.x;
    int wid = tid >> 6, lane = tid & 63;
    float x[4];
    float s = 0.f;
    #pragma unroll
    for (int i = 0; i < 4; ++i) { x[i] = bs2f(px[tid + i * 256]); s += x[i]; }
    s = wave_sum(s);
    if (lane == 0) red[wid] = s;
    __syncthreads();
    float mean = (red[0] + red[1] + red[2] + red[3]) * (1.0f / DMODEL);
    float s2 = 0.f;
    #pragma unroll
    for (int i = 0; i < 4; ++i) { float d = x[i] - mean; s2 += d * d; }
    s2 = wave_sum(s2);
    if (lane == 0) red2[wid] = s2;
    __syncthreads();
    float var = (red2[0] + red2[1] + red2[2] + red2[3]) * (1.0f / DMODEL);
    float r = 1.0f / sqrtf(var + 1e-5f);
    #pragma unroll
    for (int i = 0; i < 4; ++i) {
        int d = tid + i * 256;
        po[d] = (x[i] - mean) * r * g[d] + b[d];
    }
}

// ------------- transpose+convert bodies: W f32 [K][N] -> WT bf16 [N][K] -------------
__device__ void convT_body(char* smem, int kx, int ny, const float* __restrict__ W,
                           unsigned short* __restrict__ WT, int K, int N) {
    float (*t)[65] = (float(*)[65])smem;
    const int k0 = kx * 64, n0 = ny * 64;
    const int tid = threadIdx.x;
    {
        const int krow = tid >> 4, c4 = (tid & 15) * 4;
        #pragma unroll
        for (int p = 0; p < 4; ++p) {
            f32x4 gv = *(const f32x4*)&W[(long)(k0 + p * 16 + krow) * N + n0 + c4];
            #pragma unroll
            for (int j = 0; j < 4; ++j) t[p * 16 + krow][c4 + j] = gv[j];
        }
    }
    __syncthreads();
    {
        const int n = tid >> 3, kl = (tid & 7) * 8;
        #pragma unroll
        for (int p = 0; p < 2; ++p) {
            ushort8v pk;
            #pragma unroll
            for (int j = 0; j < 8; ++j) pk[j] = f2bs(t[kl + j][p * 32 + n]);
            *(ushort8v*)&WT[(long)(n0 + p * 32 + n) * K + k0 + kl] = pk;
        }
    }
}

// 512-thread variant
__device__ void convT_body512(char* smem, int kx, int ny, const float* __restrict__ W,
                              unsigned short* __restrict__ WT, int K, int N) {
    float (*t)[65] = (float(*)[65])smem;
    const int k0 = kx * 64, n0 = ny * 64;
    const int tid = threadIdx.x;
    {
        const int krow = tid >> 4, c4 = (tid & 15) * 4;   // krow 0..31
        #pragma unroll
        for (int p = 0; p < 2; ++p) {
            f32x4 gv = *(const f32x4*)&W[(long)(k0 + p * 32 + krow) * N + n0 + c4];
            #pragma unroll
            for (int j = 0; j < 4; ++j) t[p * 32 + krow][c4 + j] = gv[j];
        }
    }
    __syncthreads();
    {
        const int n = tid >> 3, kl = (tid & 7) * 8;       // n 0..63
        ushort8v pk;
        #pragma unroll
        for (int j = 0; j < 8; ++j) pk[j] = f2bs(t[kl + j][n]);
        *(ushort8v*)&WT[(long)(n0 + n) * K + k0 + kl] = pk;
    }
}

// ---------------- 256^2 8-phase bf16 MFMA GEMM body ----------------
#define STG_A(KS, H) do { \
    const unsigned short* g_ = A + (long)(bm + (H) * 128 + srow) * K + (KS) * 64 + stgch; \
    unsigned short* s_ = LDS + (((KS) & 1) * 2 + (H)) * 8192 + (w * 8) * 64; \
    gl_lds16(g_, s_); gl_lds16(g_ + 64L * K, s_ + 4096); \
} while (0)
#define STG_B(KS, H) do { \
    const unsigned short* g_ = BT + (long)(bn + (H) * 128 + srow) * K + (KS) * 64 + stgch; \
    unsigned short* s_ = LDS + 32768 + (((KS) & 1) * 2 + (H)) * 8192 + (w * 8) * 64; \
    gl_lds16(g_, s_); gl_lds16(g_ + 64L * K, s_ + 4096); \
} while (0)
#define MM2(M_, x0, x1) do { \
    acc[M_][0] = __builtin_amdgcn_mfma_f32_16x16x32_bf16(x0, bfr[0], acc[M_][0], 0, 0, 0); \
    acc[M_][0] = __builtin_amdgcn_mfma_f32_16x16x32_bf16(x1, bfr[1], acc[M_][0], 0, 0, 0); \
    acc[M_][1] = __builtin_amdgcn_mfma_f32_16x16x32_bf16(x0, bfr[2], acc[M_][1], 0, 0, 0); \
    acc[M_][1] = __builtin_amdgcn_mfma_f32_16x16x32_bf16(x1, bfr[3], acc[M_][1], 0, 0, 0); \
    acc[M_][2] = __builtin_amdgcn_mfma_f32_16x16x32_bf16(x0, bfr[4], acc[M_][2], 0, 0, 0); \
    acc[M_][2] = __builtin_amdgcn_mfma_f32_16x16x32_bf16(x1, bfr[5], acc[M_][2], 0, 0, 0); \
    acc[M_][3] = __builtin_amdgcn_mfma_f32_16x16x32_bf16(x0, bfr[6], acc[M_][3], 0, 0, 0); \
    acc[M_][3] = __builtin_amdgcn_mfma_f32_16x16x32_bf16(x1, bfr[7], acc[M_][3], 0, 0, 0); \
} while (0)
#define PHASE(Q, SPAR, STAGE_STMT, TAIL_STMT) do { \
    bf16x8 a00, a01, a10, a11; \
    if (((Q) & 3) == 0) { \
        const unsigned short* Bb_ = lBp[SPAR] + ((wc & 1) * 64 + fr) * 64; \
        bfr[0] = *(const bf16x8*)(Bb_ + rd0);        bfr[1] = *(const bf16x8*)(Bb_ + rd1); \
        bfr[2] = *(const bf16x8*)(Bb_ + 1024 + rd0); bfr[3] = *(const bf16x8*)(Bb_ + 1024 + rd1); \
        bfr[4] = *(const bf16x8*)(Bb_ + 2048 + rd0); bfr[5] = *(const bf16x8*)(Bb_ + 2048 + rd1); \
        bfr[6] = *(const bf16x8*)(Bb_ + 3072 + rd0); bfr[7] = *(const bf16x8*)(Bb_ + 3072 + rd1); \
    } \
    { const unsigned short* Ab_ = lAp[SPAR] + fr * 64; \
      a00 = *(const bf16x8*)(Ab_ + (((Q) & 3) * 2) * 1024 + rd0); \
      a01 = *(const bf16x8*)(Ab_ + (((Q) & 3) * 2) * 1024 + rd1); \
      a10 = *(const bf16x8*)(Ab_ + (((Q) & 3) * 2 + 1) * 1024 + rd0); \
      a11 = *(const bf16x8*)(Ab_ + (((Q) & 3) * 2 + 1) * 1024 + rd1); } \
    STAGE_STMT; \
    __builtin_amdgcn_s_barrier(); \
    asm volatile("s_waitcnt lgkmcnt(0)" ::: "memory"); \
    __builtin_amdgcn_sched_barrier(0); \
    __builtin_amdgcn_s_setprio(1); \
    MM2(((Q) & 3) * 2, a00, a01); \
    MM2(((Q) & 3) * 2 + 1, a10, a11); \
    __builtin_amdgcn_s_setprio(0); \
    TAIL_STMT; \
    __builtin_amdgcn_s_barrier(); \
} while (0)

template<int EPI>
__device__ void mm256_body(unsigned short* LDS, int bid, int nwg,
                           const unsigned short* __restrict__ A,
                           const unsigned short* __restrict__ BT,
                           const float* __restrict__ bias,
                           void* __restrict__ Cout, int M, int N, int K, int nbx) {
    const int tid = threadIdx.x;
    const int w = tid >> 6, lane = tid & 63;
    const int wr = w >> 2, wc = w & 3;
    const int swz = (bid & 7) * (nwg >> 3) + (bid >> 3);
    const int bm = (swz / nbx) * 256, bn = (swz % nbx) * 256;

    f32x4 acc[8][4];
    #pragma unroll
    for (int m = 0; m < 8; ++m)
        #pragma unroll
        for (int n = 0; n < 4; ++n)
            acc[m][n] = (f32x4){0.f, 0.f, 0.f, 0.f};

    const int fr = lane & 15, kg = lane >> 4;
    const int rd0 = 8 * (kg ^ (lane & 7)), rd1 = 8 * ((kg + 4) ^ (lane & 7));
    const int stgch = 8 * ((lane & 7) ^ (lane >> 3));
    const int srow = w * 8 + (lane >> 3);
    unsigned short* const lAp[2] = { LDS + wr * 8192, LDS + (2 + wr) * 8192 };
    unsigned short* const lBp[2] = { LDS + 32768 + (wc >> 1) * 8192,
                                     LDS + 32768 + (2 + (wc >> 1)) * 8192 };
    bf16x8 bfr[8];

    STG_B(0, 0); STG_B(0, 1); STG_A(0, 0); STG_A(0, 1); STG_B(1, 0); STG_B(1, 1);
    asm volatile("s_waitcnt vmcnt(4)" ::: "memory");
    __builtin_amdgcn_sched_barrier(0);
    __builtin_amdgcn_s_barrier();

    const int T = K >> 7;
    for (int t = 0; t < T; ++t) {
        const int s = 2 * t;
        const bool nl = (t < T - 1);
        PHASE(0, 0, STG_A(s + 1, 0), );
        PHASE(1, 0, STG_A(s + 1, 1), );
        PHASE(2, 0, if (nl) STG_B(s + 2, 0), );
        PHASE(3, 0, if (nl) STG_B(s + 2, 1),
              if (nl) { asm volatile("s_waitcnt vmcnt(4)" ::: "memory"); } else { asm volatile("s_waitcnt vmcnt(0)" ::: "memory"); } __builtin_amdgcn_sched_barrier(0); );
        PHASE(4, 1, if (nl) STG_A(s + 2, 0), );
        PHASE(5, 1, if (nl) STG_A(s + 2, 1), );
        PHASE(6, 1, if (nl) STG_B(s + 3, 0), );
        PHASE(7, 1, if (nl) STG_B(s + 3, 1),
              if (nl) { asm volatile("s_waitcnt vmcnt(4)" ::: "memory"); __builtin_amdgcn_sched_barrier(0); } );
    }

    const int r0 = (lane >> 4) * 4;
    #pragma unroll
    for (int n = 0; n < 4; ++n) {
        int colb = bn + wc * 64 + n * 16;
        float bv = bias[colb + fr];
        #pragma unroll
        for (int m = 0; m < 8; ++m) {
            int rowb = bm + wr * 128 + m * 16 + r0;
            if (EPI == 3) {
                unsigned short* qkvB = (unsigned short*)Cout;
                int which = colb >> 10, hh = (colb & 1023) >> 6, dbase = colb & 63;
                int b_ = rowb >> 11, s_ = rowb & 2047;
                long bh2 = b_ * 16 + hh;
                float v[4];
                #pragma unroll
                for (int r = 0; r < 4; ++r) v[r] = acc[m][n][r] + bv;
                if (which == 2) {
                    ushort4v pk;
                    #pragma unroll
                    for (int r = 0; r < 4; ++r) pk[r] = f2bs(v[r]);
                    *(ushort4v*)&qkvB[8388608L + (bh2 * 64 + dbase + fr) * 2048 + s_] = pk;
                } else {
                    unsigned short* dst = qkvB + (long)which * 4194304L +
                                          (bh2 * 2048 + s_) * 64 + dbase + fr;
                    #pragma unroll
                    for (int r = 0; r < 4; ++r) dst[r * 64] = f2bs(v[r]);
                }
            } else {
                #pragma unroll
                for (int r = 0; r < 4; ++r) {
                    long row = rowb + r, col = colb + fr;
                    float v = acc[m][n][r] + bv;
                    v = 0.5f * v * (1.0f + erff(v * 0.70710678118f));
                    ((__hip_bfloat16*)Cout)[row * N + col] = __float2bfloat16(v);
                }
            }
        }
    }
}

template<int EPI>
__global__ __launch_bounds__(512, 1)
void mm_mfma256(const unsigned short* __restrict__ A,
                const unsigned short* __restrict__ BT,
                const float* __restrict__ bias,
                void* __restrict__ Cout, int M, int N, int K, int nbx) {
    extern __shared__ unsigned short LDS[];
    mm256_body<EPI>(LDS, blockIdx.x, gridDim.x, A, BT, bias, Cout, M, N, K, nbx);
}

// 256^2 GEMM (nMM blocks) + convT -> WT2 (remaining blocks), 512 thr
template<int EPI>
__global__ __launch_bounds__(512, 1)
void fused_mm256_convT(const unsigned short* __restrict__ A,
                       const unsigned short* __restrict__ BT,
                       const float* __restrict__ bias,
                       void* __restrict__ Cout, int M, int N, int K, int nbx,
                       const float* __restrict__ W2, unsigned short* __restrict__ WT2,
                       int K2, int N2, int nMM) {
    extern __shared__ unsigned short LDS[];
    int bid = blockIdx.x;
    if (bid < nMM) {
        mm256_body<EPI>(LDS, bid, nMM, A, BT, bias, Cout, M, N, K, nbx);
    } else {
        int r = bid - nMM, kt = K2 >> 6;
        convT_body512((char*)LDS, r % kt, r / kt, W2, WT2, K2, N2);
    }
}

// ---------------- n64 GEMM body (3-buffer, 2-deep prefetch, vmcnt(6)); bf16 residual ----------------
__device__ void n64_body(char* smem, int bx, int by,
                         const unsigned short* __restrict__ A,
                         const unsigned short* __restrict__ BT,
                         const float* __restrict__ bias,
                         const unsigned short* __restrict__ R,
                         unsigned short* __restrict__ Cout, int M, int N, int K) {
    unsigned short* As = (unsigned short*)smem;
    unsigned short* Bs = As + 3 * 128 * 32;
    const int tid = threadIdx.x;
    const int w = tid >> 6, lane = tid & 63;
    const int bm = by * 128, bn = bx * 64;
    const int wr = (w >> 1) * 64, wc = (w & 1) * 32;

    f32x4 acc[4][2];
    #pragma unroll
    for (int m = 0; m < 4; ++m)
        #pragma unroll
        for (int n = 0; n < 2; ++n)
            acc[m][n] = (f32x4){0.f, 0.f, 0.f, 0.f};

    const int lrow = lane >> 2;
    const int lcol = (lane & 3) * 8;
    const unsigned short* gA = A + (long)(bm + w * 32 + lrow) * K + lcol;
    const unsigned short* gB = BT + (long)(bn + w * 16 + lrow) * K + lcol;

#define N64_STAGE(K0, BB) do { \
    gl_lds16(gA + (K0),          &As[(BB) * 4096 + (w * 32) * 32]); \
    gl_lds16(gA + (K0) + 16 * K, &As[(BB) * 4096 + (w * 32 + 16) * 32]); \
    gl_lds16(gB + (K0),          &Bs[(BB) * 2048 + (w * 16) * 32]); \
} while (0)

    const int T = K >> 5;
    N64_STAGE(0, 0);
    if (T > 1) N64_STAGE(32, 1);

    for (int t = 0; t < T; ++t) {
        const int buf = t % 3;
        if (t + 2 < T) {
            N64_STAGE((t + 2) * 32, (t + 2) % 3);
            asm volatile("s_waitcnt vmcnt(6)" ::: "memory");
        } else if (t + 1 < T) {
            asm volatile("s_waitcnt vmcnt(3)" ::: "memory");
        } else {
            asm volatile("s_waitcnt vmcnt(0)" ::: "memory");
        }
        __builtin_amdgcn_sched_barrier(0);
        __builtin_amdgcn_s_barrier();

        bf16x8 a[4], b[2];
        #pragma unroll
        for (int m = 0; m < 4; ++m)
            a[m] = *(const bf16x8*)&As[buf * 4096 + (wr + m * 16 + (lane & 15)) * 32 + (lane >> 4) * 8];
        #pragma unroll
        for (int n = 0; n < 2; ++n)
            b[n] = *(const bf16x8*)&Bs[buf * 2048 + (wc + n * 16 + (lane & 15)) * 32 + (lane >> 4) * 8];
        #pragma unroll
        for (int m = 0; m < 4; ++m)
            #pragma unroll
            for (int n = 0; n < 2; ++n)
                acc[m][n] = __builtin_amdgcn_mfma_f32_16x16x32_bf16(a[m], b[n], acc[m][n], 0, 0, 0);

        __builtin_amdgcn_s_barrier();
    }
#undef N64_STAGE

    const int r0 = (lane >> 4) * 4, cc = lane & 15;
    #pragma unroll
    for (int n = 0; n < 2; ++n) {
        int colb = bn + wc + n * 16;
        float bv = bias[colb + cc];
        #pragma unroll
        for (int m = 0; m < 4; ++m) {
            int rowb = bm + wr + m * 16 + r0;
            #pragma unroll
            for (int r = 0; r < 4; ++r) {
                long row = rowb + r, col = colb + cc;
                float v = acc[m][n][r] + bv + bs2f(R[row * N + col]);
                Cout[row * N + col] = f2bs(v);
            }
        }
    }
}

// ---------------- MFMA flash attention body, QBLK=128, KVBLK=128, 8 waves ----------------
// K double-buffered + counted vmcnt; diag chunk skips fully-masked tiles (n > w).
__device__ void attn_body(char* smem, int bh, int qb,
                          const unsigned short* __restrict__ qB,
                          const unsigned short* __restrict__ kB,
                          const unsigned short* __restrict__ vT,
                          __hip_bfloat16* __restrict__ z) {
    const int tid = threadIdx.x, w = tid >> 6, lane = tid & 63;
    const int arow = lane & 15, kg = lane >> 4;
    unsigned short* KB0 = (unsigned short*)smem;
    unsigned short* KB1 = KB0 + 128 * 64;
    unsigned short* Vs  = KB1 + 128 * 64;
    unsigned short* Ps  = Vs + 64 * 128 + w * 16 * 128;

    const long kvbase = (long)bh * (2048 * 64);

    bf16x8 qa[2];
    {
        const unsigned short* q0 = qB + kvbase + (long)(qb + w * 16 + arow) * 64 + kg * 8;
        qa[0] = *(const bf16x8*)(q0);
        qa[1] = *(const bf16x8*)(q0 + 32);
    }

    f32x4 po[4];
    float mrow[4], lrow[4];
    #pragma unroll
    for (int i = 0; i < 4; ++i) {
        po[i] = (f32x4){0.f, 0.f, 0.f, 0.f};
        mrow[i] = -1e30f; lrow[i] = 0.f;
    }

    const int ksrow = lane >> 3;
    const int kschunk = (lane & 7) ^ ksrow;
    const int vsr = lane >> 4;
    const int cmax = qb >> 7;

    const unsigned short* kSrc = kB + kvbase + (long)(w * 16 + ksrow) * 64 + kschunk * 8;

#define STAGE_K(c, KBp) do { \
    gl_lds16(kSrc + (long)(c) * 128 * 64,          &(KBp)[(w * 16) * 64]); \
    gl_lds16(kSrc + (long)(c) * 128 * 64 + 8 * 64, &(KBp)[(w * 16 + 8) * 64]); \
} while (0)
#define STAGE_V(c) do { \
    _Pragma("unroll") \
    for (int i_ = 0; i_ < 2; ++i_) { \
        int d_ = w * 8 + i_ * 4 + vsr; \
        int sch_ = (lane & 15) ^ (d_ & 7); \
        gl_lds16(vT + kvbase + (long)d_ * 2048 + (c) * 128 + sch_ * 8, \
                 &Vs[(w * 8 + i_ * 4) * 128]); \
    } \
} while (0)

    STAGE_K(0, KB0);
    STAGE_V(0);

    for (int c = 0; c <= cmax; ++c) {
        unsigned short* KBcur = (c & 1) ? KB1 : KB0;
        if (c < cmax) {
            STAGE_K(c + 1, (c & 1) ? KB0 : KB1);
            asm volatile("s_waitcnt vmcnt(2)" ::: "memory");
        } else {
            asm volatile("s_waitcnt vmcnt(0)" ::: "memory");
        }
        __builtin_amdgcn_sched_barrier(0);
        __builtin_amdgcn_s_barrier();
        __builtin_amdgcn_sched_barrier(0);

        const bool diag = (c == cmax);

        f32x4 s[8];
        #pragma unroll
        for (int n = 0; n < 8; ++n) {
            s[n] = (f32x4){0.f, 0.f, 0.f, 0.f};
            // Diagonal chunk: tile n is fully masked for wave w when n > w
            // (min key 16n > max row 16w+15). Skip dead K-reads + MFMAs;
            // s stays 0 and the mask below sets it to -1e30 (exp -> 0).
            if (!diag || n <= w) {
                int row = n * 16 + arow, sw = row & 7;
                bf16x8 kb0 = *(const bf16x8*)&KBcur[row * 64 + (kg ^ sw) * 8];
                bf16x8 kb1 = *(const bf16x8*)&KBcur[row * 64 + ((4 + kg) ^ sw) * 8];
                s[n] = __builtin_amdgcn_mfma_f32_16x16x32_bf16(qa[0], kb0, s[n], 0, 0, 0);
                s[n] = __builtin_amdgcn_mfma_f32_16x16x32_bf16(qa[1], kb1, s[n], 0, 0, 0);
            }
        }

        #pragma unroll
        for (int n = 0; n < 8; ++n)
            #pragma unroll
            for (int r = 0; r < 4; ++r) {
                float v = s[n][r] * 0.125f;
                if (diag) {
                    int key = c * 128 + n * 16 + arow;
                    int qrow = qb + w * 16 + kg * 4 + r;
                    if (key > qrow) v = -1e30f;
                }
                s[n][r] = v;
            }

        #pragma unroll
        for (int r = 0; r < 4; ++r) {
            float rm = s[0][r];
            #pragma unroll
            for (int n = 1; n < 8; ++n) rm = fmaxf(rm, s[n][r]);
            #pragma unroll
            for (int off = 1; off < 16; off <<= 1)
                rm = fmaxf(rm, __shfl_xor(rm, off));
            float mnew = fmaxf(mrow[r], rm);
            float esc = expf(mrow[r] - mnew);
            float rs = 0.f;
            #pragma unroll
            for (int n = 0; n < 8; ++n) {
                float p = expf(s[n][r] - mnew);
                s[n][r] = p;
                rs += p;
            }
            #pragma unroll
            for (int off = 1; off < 16; off <<= 1)
                rs += __shfl_xor(rs, off);
            lrow[r] = lrow[r] * esc + rs;
            #pragma unroll
            for (int dt = 0; dt < 4; ++dt) po[dt][r] *= esc;
            mrow[r] = mnew;
        }

        #pragma unroll
        for (int n = 0; n < 8; ++n) {
            int col = n * 16 + arow;
            int chunk = col >> 3, cw = col & 7;
            #pragma unroll
            for (int r = 0; r < 4; ++r) {
                int row = kg * 4 + r;
                Ps[row * 128 + ((chunk ^ (row & 7)) * 8 + cw)] = f2bs(s[n][r]);
            }
        }

        bf16x8 pa[4];
        #pragma unroll
        for (int ks = 0; ks < 4; ++ks)
            pa[ks] = *(const bf16x8*)&Ps[arow * 128 + (((ks * 4 + kg) ^ (arow & 7)) * 8)];
        #pragma unroll
        for (int dt = 0; dt < 4; ++dt) {
            int vrow = dt * 16 + arow, sw = vrow & 7;
            #pragma unroll
            for (int ks = 0; ks < 4; ++ks) {
                bf16x8 vb = *(const bf16x8*)&Vs[vrow * 128 + (((ks * 4 + kg) ^ sw) * 8)];
                po[dt] = __builtin_amdgcn_mfma_f32_16x16x32_bf16(pa[ks], vb, po[dt], 0, 0, 0);
            }
        }
        __builtin_amdgcn_sched_barrier(0);
        __builtin_amdgcn_s_barrier();
        __builtin_amdgcn_sched_barrier(0);
        if (c < cmax) STAGE_V(c + 1);
    }
#undef STAGE_K
#undef STAGE_V

    const int b_ = bh >> 4, hofs = (bh & 15) * 64;
    #pragma unroll
    for (int dt = 0; dt < 4; ++dt)
        #pragma unroll
        for (int r = 0; r < 4; ++r) {
            long row = (long)b_ * 2048 + qb + w * 16 + kg * 4 + r;
            z[row * 1024 + hofs + dt * 16 + arow] = __float2bfloat16(po[dt][r] / lrow[r]);
        }
}

// ---------------- fused kernels ----------------
__global__ __launch_bounds__(256)
void fused_embed_convT(const int* __restrict__ x, const float* __restrict__ wte,
                       const float* __restrict__ wpe, unsigned short* __restrict__ h,
                       const float* __restrict__ W, unsigned short* __restrict__ WT,
                       int K, int N, int nEmb) {
    extern __shared__ char smem[];
    int bid = blockIdx.x;
    if (bid < nEmb) {
        embed_body(bid, x, wte, wpe, h);
    } else {
        int r = bid - nEmb, kt = K >> 6;
        convT_body(smem, r % kt, r / kt, W, WT, K, N);
    }
}

// attn QBLK=128 heavy-first (nAttn) + convT -> WT2; 512 thr
__global__ __launch_bounds__(512)
void fused_attn_convT(const unsigned short* __restrict__ qB,
                      const unsigned short* __restrict__ kB,
                      const unsigned short* __restrict__ vT,
                      __hip_bfloat16* __restrict__ z,
                      const float* __restrict__ W2, unsigned short* __restrict__ WT2,
                      int K2, int N2, int nAttn) {
    extern __shared__ char smem[];
    int bid = blockIdx.x;
    if (bid < nAttn) {
        int bh = bid & 31;
        int qblk = 15 - (bid >> 5);           // heavy-first
        attn_body(smem, bh, qblk * 128, qB, kB, vT, z);
    } else {
        int r = bid - nAttn, kt = K2 >> 6;
        convT_body512(smem, r % kt, r / kt, W2, WT2, K2, N2);
    }
}

// n64 GEMM (nMM, bx=bid%nbx) + optional convT -> WT2 (nConv blocks)
__global__ __launch_bounds__(256)
void fused_n64_convT(const unsigned short* __restrict__ A,
                     const unsigned short* __restrict__ BT,
                     const float* __restrict__ bias, const unsigned short* __restrict__ R,
                     unsigned short* __restrict__ Cout, int M, int N, int K, int nbx,
                     const float* __restrict__ W2, unsigned short* __restrict__ WT2,
                     int K2, int N2, int nMM) {
    extern __shared__ char smem[];
    int bid = blockIdx.x;
    if (bid < nMM) {
        n64_body(smem, bid % nbx, bid / nbx, A, BT, bias, R, Cout, M, N, K);
    } else {
        int r = bid - nMM, kt = K2 >> 6;
        convT_body(smem, r % kt, r / kt, W2, WT2, K2, N2);
    }
}

// ---------------- head ----------------
__global__ void head_kernel(const float* __restrict__ hl, const float* __restrict__ W,
                            float* __restrict__ out) {
    __shared__ float hs[2 * DMODEL];
    int tid = threadIdx.x;
    #pragma unroll
    for (int i = 0; i < 8; ++i) hs[tid + i * 256] = hl[tid + i * 256];
    __syncthreads();
    int v = blockIdx.x * 256 + tid;
    if (v >= VOCAB) return;
    float a0 = 0.f, a1 = 0.f;
    for (int d = 0; d < DMODEL; ++d) {
        float wv = W[(long)d * VOCAB + v];
        a0 += hs[d] * wv;
        a1 += hs[DMODEL + d] * wv;
    }
    out[v] = a0;
    out[VOCAB + v] = a1;
}

extern "C" void kernel_launch(void* const* d_in, const int* in_sizes, int n_in,
                              void* d_out, int out_size, void* d_ws, size_t ws_size,
                              hipStream_t stream) {
    const int*   x      = (const int*)  d_in[0];
    const float* wte    = (const float*)d_in[1];
    const float* wpe    = (const float*)d_in[2];
    const float* ln1_g  = (const float*)d_in[3];
    const float* ln1_b  = (const float*)d_in[4];
    const float* w_qkv  = (const float*)d_in[5];
    const float* b_qkv  = (const float*)d_in[6];
    const float* w_proj = (const float*)d_in[7];
    const float* b_proj = (const float*)d_in[8];
    const float* ln2_g  = (const float*)d_in[9];
    const float* ln2_b  = (const float*)d_in[10];
    const float* w_fc   = (const float*)d_in[11];
    const float* b_fc   = (const float*)d_in[12];
    const float* w_cp   = (const float*)d_in[13];
    const float* b_cp   = (const float*)d_in[14];
    const float* lnf_g  = (const float*)d_in[15];
    const float* lnf_b  = (const float*)d_in[16];
    const float* w_head = (const float*)d_in[17];
    float* out = (float*)d_out;

    char* ws = (char*)d_ws;
    unsigned short* h     = (unsigned short*)ws;                    // 8 MB (bf16)
    unsigned short* qkvB  = (unsigned short*)(ws + (8L << 20));     // 24 MB
    unsigned short* y_bf  = (unsigned short*)(ws + (32L << 20));    // 8 MB
    __hip_bfloat16* z_bf  = (__hip_bfloat16*)(ws + (40L << 20));    // 8 MB
    unsigned short* fc_bf = (unsigned short*)(ws + (48L << 20));    // 32 MB
    unsigned short* wT_a  = (unsigned short*)(ws + (80L << 20));    // 8 MB (fc)
    unsigned short* wT_b  = (unsigned short*)(ws + (89L << 20));    // 8 MB (proj)
    unsigned short* wT_c  = (unsigned short*)(ws + (98L << 20));    // 8 MB (cp)
    unsigned short* wT_q  = (unsigned short*)(ws + (107L << 20));   // 8 MB (qkv)
    float*          hl    = (float*)(ws + (116L << 20));            // 8 KB

    const int SM_CONV = 16640;   // 64*65*4
    const int SM_ATTN = 81920;   // KB 2x16K + Vs 16K + Ps 32K
    const int SM_N64  = 36864;   // As(24K)+Bs(12K)

    // P: embed (4096) + convT qkv layer 0 (768) -> wT_q
    fused_embed_convT<<<4096 + 768, 256, SM_CONV, stream>>>(
        x, wte, wpe, h, w_qkv, wT_q, 1024, 3072, 4096);

    for (int l = 0; l < NLAYER; ++l) {
        // A: LN1 (wave-per-row, bf16 in/out)
        ln_wave<<<NTOK / 4, 256, 0, stream>>>(h, y_bf, ln1_g + l * DMODEL, ln1_b + l * DMODEL);

        // B: qkv GEMM (192) + convT proj -> wT_b (256)
        fused_mm256_convT<3><<<192 + 256, 512, 131072, stream>>>(
            y_bf, wT_q, b_qkv + l * 3072, qkvB, NTOK, 3072, 1024, 12,
            w_proj + (long)l * DMODEL * DMODEL, wT_b, 1024, 1024, 192);

        // C: attn QBLK=128 (512) + convT cp -> wT_c (1024)
        fused_attn_convT<<<512 + 1024, 512, SM_ATTN, stream>>>(
            qkvB, qkvB + 4194304L, qkvB + 8388608L, z_bf,
            w_cp + (long)l * 4096 * DMODEL, wT_c, 4096, 1024, 512);

        // D: proj GEMM (+bf16 residual) + convT fc -> wT_a (1024)
        fused_n64_convT<<<512 + 1024, 256, SM_N64, stream>>>(
            (const unsigned short*)z_bf, wT_b, b_proj + l * DMODEL, h, h,
            NTOK, 1024, 1024, 16,
            w_fc + (long)l * DMODEL * 4096, wT_a, 1024, 4096, 512);

        // E: LN2 (wave-per-row)
        ln_wave<<<NTOK / 4, 256, 0, stream>>>(h, y_bf, ln2_g + l * DMODEL, ln2_b + l * DMODEL);

        // F: fc GEMM (256^2 8-phase, gelu; reads wT_a)
        mm_mfma256<2><<<256, 512, 131072, stream>>>(
            y_bf, wT_a, b_fc + l * 4096, fc_bf, NTOK, 4096, 1024, 16);

        // G: cp GEMM (+bf16 residual) + convT qkv(l+1) -> wT_q (768; none on last layer)
        int nConv = (l + 1 < NLAYER) ? 768 : 0;
        fused_n64_convT<<<512 + nConv, 256, SM_N64, stream>>>(
            fc_bf, wT_c, b_cp + l * DMODEL, h, h, NTOK, 1024, 4096, 16,
            w_qkv + (long)(l + 1) * DMODEL * 3072, wT_q, 1024, 3072, 512);
    }

    ln_final<<<BATCH, 256, 0, stream>>>(h + (long)(SEQ - 1) * DMODEL, hl,
                                        lnf_g, lnf_b, (long)SEQ * DMODEL);
    head_kernel<<<(VOCAB + 255) / 256, 256, 0, stream>>>(hl, w_head, out);
}

// Round 22
// 2219.461 us; speedup vs baseline: 1.0060x; 1.0060x over previous
//
#include <hip/hip_runtime.h>
#include <hip/hip_bf16.h>
#include <math.h>

#define VOCAB 50257
#define CTX 2048
#define DMODEL 1024
#define NHEAD 16
#define NLAYER 8
#define DHEAD 64
#define BATCH 2
#define SEQ 2048
#define NTOK (BATCH * SEQ)   // 4096

typedef __bf16 bf16x8 __attribute__((ext_vector_type(8)));
typedef float  f32x4  __attribute__((ext_vector_type(4)));
typedef unsigned short ushort4v __attribute__((ext_vector_type(4)));
typedef unsigned short ushort8v __attribute__((ext_vector_type(8)));

__device__ inline void gl_lds16(const void* g, void* l) {
    __builtin_amdgcn_global_load_lds(
        (const __attribute__((address_space(1))) unsigned int*)g,
        (__attribute__((address_space(3))) unsigned int*)l, 16, 0, 0);
}

__device__ inline unsigned short f2bs(float v) {
    __hip_bfloat16 t = __float2bfloat16(v);
    return *(unsigned short*)&t;
}
__device__ inline float bs2f(unsigned short u) {
    return __uint_as_float(((unsigned)u) << 16);
}

// ---------------- embedding body: h (bf16) = wte[x] + wpe[pos] ----------------
__device__ void embed_body(int t, const int* __restrict__ x,
                           const float* __restrict__ wte,
                           const float* __restrict__ wpe,
                           unsigned short* __restrict__ h) {
    int s = t & (SEQ - 1);
    int tok = x[t];
    const float* pe = wpe + (long)s * DMODEL;
    const float* te = wte + (long)tok * DMODEL;
    unsigned short* ph = h + (long)t * DMODEL;
    int d = threadIdx.x * 4;
    f32x4 t4 = *(const f32x4*)&te[d];
    f32x4 p4 = *(const f32x4*)&pe[d];
    ushort4v o;
    #pragma unroll
    for (int j = 0; j < 4; ++j) o[j] = f2bs(t4[j] + p4[j]);
    *(ushort4v*)&ph[d] = o;
}

// ---------------- layernorm ----------------
__device__ inline float wave_sum(float v) {
    for (int off = 32; off; off >>= 1) v += __shfl_xor(v, off);
    return v;
}

// wave-per-row LN, bf16 in -> bf16 out
__global__ void ln_wave(const unsigned short* __restrict__ in,
                        unsigned short* __restrict__ out,
                        const float* __restrict__ g, const float* __restrict__ b) {
    const int w = threadIdx.x >> 6, lane = threadIdx.x & 63;
    const int row = blockIdx.x * 4 + w;
    const unsigned short* px = in + (long)row * DMODEL;
    ushort8v u[2];
    u[0] = *(const ushort8v*)&px[lane * 16];
    u[1] = *(const ushort8v*)&px[lane * 16 + 8];
    float x[16];
    float s = 0.f;
    #pragma unroll
    for (int i = 0; i < 16; ++i) { x[i] = bs2f(u[i >> 3][i & 7]); s += x[i]; }
    s = wave_sum(s);
    const float mean = s * (1.0f / DMODEL);
    float s2 = 0.f;
    #pragma unroll
    for (int i = 0; i < 16; ++i) { float d = x[i] - mean; s2 += d * d; }
    s2 = wave_sum(s2);
    const float r = 1.0f / sqrtf(s2 * (1.0f / DMODEL) + 1e-5f);
    unsigned short* po = out + (long)row * DMODEL;
    const int d0 = lane * 16;
    #pragma unroll
    for (int p = 0; p < 2; ++p) {
        ushort8v pk;
        #pragma unroll
        for (int j = 0; j < 8; ++j) {
            int d = d0 + p * 8 + j;
            pk[j] = f2bs((x[p * 8 + j] - mean) * r * g[d] + b[d]);
        }
        *(ushort8v*)&po[d0 + p * 8] = pk;
    }
}

// final LN: bf16 in -> f32 out (2 rows)
__global__ void ln_final(const unsigned short* __restrict__ in, float* __restrict__ out,
                         const float* __restrict__ g, const float* __restrict__ b,
                         long row_stride) {
    __shared__ float red[4], red2[4];
    int row = blockIdx.x;
    const unsigned short* px = in + (long)row * row_stride;
    float* po = out + (long)row * DMODEL;
    int tid = threadIdx.x;
    int wid = tid >> 6, lane = tid & 63;
    float x[4];
    float s = 0.f;
    #pragma unroll
    for (int i = 0; i < 4; ++i) { x[i] = bs2f(px[tid + i * 256]); s += x[i]; }
    s = wave_sum(s);
    if (lane == 0) red[wid] = s;
    __syncthreads();
    float mean = (red[0] + red[1] + red[2] + red[3]) * (1.0f / DMODEL);
    float s2 = 0.f;
    #pragma unroll
    for (int i = 0; i < 4; ++i) { float d = x[i] - mean; s2 += d * d; }
    s2 = wave_sum(s2);
    if (lane == 0) red2[wid] = s2;
    __syncthreads();
    float var = (red2[0] + red2[1] + red2[2] + red2[3]) * (1.0f / DMODEL);
    float r = 1.0f / sqrtf(var + 1e-5f);
    #pragma unroll
    for (int i = 0; i < 4; ++i) {
        int d = tid + i * 256;
        po[d] = (x[i] - mean) * r * g[d] + b[d];
    }
}

// ------------- transpose+convert bodies: W f32 [K][N] -> WT bf16 [N][K] -------------
__device__ void convT_body(char* smem, int kx, int ny, const float* __restrict__ W,
                           unsigned short* __restrict__ WT, int K, int N) {
    float (*t)[65] = (float(*)[65])smem;
    const int k0 = kx * 64, n0 = ny * 64;
    const int tid = threadIdx.x;
    {
        const int krow = tid >> 4, c4 = (tid & 15) * 4;
        #pragma unroll
        for (int p = 0; p < 4; ++p) {
            f32x4 gv = *(const f32x4*)&W[(long)(k0 + p * 16 + krow) * N + n0 + c4];
            #pragma unroll
            for (int j = 0; j < 4; ++j) t[p * 16 + krow][c4 + j] = gv[j];
        }
    }
    __syncthreads();
    {
        const int n = tid >> 3, kl = (tid & 7) * 8;
        #pragma unroll
        for (int p = 0; p < 2; ++p) {
            ushort8v pk;
            #pragma unroll
            for (int j = 0; j < 8; ++j) pk[j] = f2bs(t[kl + j][p * 32 + n]);
            *(ushort8v*)&WT[(long)(n0 + p * 32 + n) * K + k0 + kl] = pk;
        }
    }
}

// 512-thread variant
__device__ void convT_body512(char* smem, int kx, int ny, const float* __restrict__ W,
                              unsigned short* __restrict__ WT, int K, int N) {
    float (*t)[65] = (float(*)[65])smem;
    const int k0 = kx * 64, n0 = ny * 64;
    const int tid = threadIdx.x;
    {
        const int krow = tid >> 4, c4 = (tid & 15) * 4;   // krow 0..31
        #pragma unroll
        for (int p = 0; p < 2; ++p) {
            f32x4 gv = *(const f32x4*)&W[(long)(k0 + p * 32 + krow) * N + n0 + c4];
            #pragma unroll
            for (int j = 0; j < 4; ++j) t[p * 32 + krow][c4 + j] = gv[j];
        }
    }
    __syncthreads();
    {
        const int n = tid >> 3, kl = (tid & 7) * 8;       // n 0..63
        ushort8v pk;
        #pragma unroll
        for (int j = 0; j < 8; ++j) pk[j] = f2bs(t[kl + j][n]);
        *(ushort8v*)&WT[(long)(n0 + n) * K + k0 + kl] = pk;
    }
}

// ---------------- 256^2 8-phase bf16 MFMA GEMM body ----------------
#define STG_A(KS, H) do { \
    const unsigned short* g_ = A + (long)(bm + (H) * 128 + srow) * K + (KS) * 64 + stgch; \
    unsigned short* s_ = LDS + (((KS) & 1) * 2 + (H)) * 8192 + (w * 8) * 64; \
    gl_lds16(g_, s_); gl_lds16(g_ + 64L * K, s_ + 4096); \
} while (0)
#define STG_B(KS, H) do { \
    const unsigned short* g_ = BT + (long)(bn + (H) * 128 + srow) * K + (KS) * 64 + stgch; \
    unsigned short* s_ = LDS + 32768 + (((KS) & 1) * 2 + (H)) * 8192 + (w * 8) * 64; \
    gl_lds16(g_, s_); gl_lds16(g_ + 64L * K, s_ + 4096); \
} while (0)
#define MM2(M_, x0, x1) do { \
    acc[M_][0] = __builtin_amdgcn_mfma_f32_16x16x32_bf16(x0, bfr[0], acc[M_][0], 0, 0, 0); \
    acc[M_][0] = __builtin_amdgcn_mfma_f32_16x16x32_bf16(x1, bfr[1], acc[M_][0], 0, 0, 0); \
    acc[M_][1] = __builtin_amdgcn_mfma_f32_16x16x32_bf16(x0, bfr[2], acc[M_][1], 0, 0, 0); \
    acc[M_][1] = __builtin_amdgcn_mfma_f32_16x16x32_bf16(x1, bfr[3], acc[M_][1], 0, 0, 0); \
    acc[M_][2] = __builtin_amdgcn_mfma_f32_16x16x32_bf16(x0, bfr[4], acc[M_][2], 0, 0, 0); \
    acc[M_][2] = __builtin_amdgcn_mfma_f32_16x16x32_bf16(x1, bfr[5], acc[M_][2], 0, 0, 0); \
    acc[M_][3] = __builtin_amdgcn_mfma_f32_16x16x32_bf16(x0, bfr[6], acc[M_][3], 0, 0, 0); \
    acc[M_][3] = __builtin_amdgcn_mfma_f32_16x16x32_bf16(x1, bfr[7], acc[M_][3], 0, 0, 0); \
} while (0)
#define PHASE(Q, SPAR, STAGE_STMT, TAIL_STMT) do { \
    bf16x8 a00, a01, a10, a11; \
    if (((Q) & 3) == 0) { \
        const unsigned short* Bb_ = lBp[SPAR] + ((wc & 1) * 64 + fr) * 64; \
        bfr[0] = *(const bf16x8*)(Bb_ + rd0);        bfr[1] = *(const bf16x8*)(Bb_ + rd1); \
        bfr[2] = *(const bf16x8*)(Bb_ + 1024 + rd0); bfr[3] = *(const bf16x8*)(Bb_ + 1024 + rd1); \
        bfr[4] = *(const bf16x8*)(Bb_ + 2048 + rd0); bfr[5] = *(const bf16x8*)(Bb_ + 2048 + rd1); \
        bfr[6] = *(const bf16x8*)(Bb_ + 3072 + rd0); bfr[7] = *(const bf16x8*)(Bb_ + 3072 + rd1); \
    } \
    { const unsigned short* Ab_ = lAp[SPAR] + fr * 64; \
      a00 = *(const bf16x8*)(Ab_ + (((Q) & 3) * 2) * 1024 + rd0); \
      a01 = *(const bf16x8*)(Ab_ + (((Q) & 3) * 2) * 1024 + rd1); \
      a10 = *(const bf16x8*)(Ab_ + (((Q) & 3) * 2 + 1) * 1024 + rd0); \
      a11 = *(const bf16x8*)(Ab_ + (((Q) & 3) * 2 + 1) * 1024 + rd1); } \
    STAGE_STMT; \
    __builtin_amdgcn_s_barrier(); \
    asm volatile("s_waitcnt lgkmcnt(0)" ::: "memory"); \
    __builtin_amdgcn_sched_barrier(0); \
    __builtin_amdgcn_s_setprio(1); \
    MM2(((Q) & 3) * 2, a00, a01); \
    MM2(((Q) & 3) * 2 + 1, a10, a11); \
    __builtin_amdgcn_s_setprio(0); \
    TAIL_STMT; \
    __builtin_amdgcn_s_barrier(); \
} while (0)

template<int EPI>
__device__ void mm256_body(unsigned short* LDS, int bid, int nwg,
                           const unsigned short* __restrict__ A,
                           const unsigned short* __restrict__ BT,
                           const float* __restrict__ bias,
                           void* __restrict__ Cout, int M, int N, int K, int nbx) {
    const int tid = threadIdx.x;
    const int w = tid >> 6, lane = tid & 63;
    const int wr = w >> 2, wc = w & 3;
    const int swz = (bid & 7) * (nwg >> 3) + (bid >> 3);
    const int bm = (swz / nbx) * 256, bn = (swz % nbx) * 256;

    f32x4 acc[8][4];
    #pragma unroll
    for (int m = 0; m < 8; ++m)
        #pragma unroll
        for (int n = 0; n < 4; ++n)
            acc[m][n] = (f32x4){0.f, 0.f, 0.f, 0.f};

    const int fr = lane & 15, kg = lane >> 4;
    const int rd0 = 8 * (kg ^ (lane & 7)), rd1 = 8 * ((kg + 4) ^ (lane & 7));
    const int stgch = 8 * ((lane & 7) ^ (lane >> 3));
    const int srow = w * 8 + (lane >> 3);
    unsigned short* const lAp[2] = { LDS + wr * 8192, LDS + (2 + wr) * 8192 };
    unsigned short* const lBp[2] = { LDS + 32768 + (wc >> 1) * 8192,
                                     LDS + 32768 + (2 + (wc >> 1)) * 8192 };
    bf16x8 bfr[8];

    STG_B(0, 0); STG_B(0, 1); STG_A(0, 0); STG_A(0, 1); STG_B(1, 0); STG_B(1, 1);
    asm volatile("s_waitcnt vmcnt(4)" ::: "memory");
    __builtin_amdgcn_sched_barrier(0);
    __builtin_amdgcn_s_barrier();

    const int T = K >> 7;
    for (int t = 0; t < T; ++t) {
        const int s = 2 * t;
        const bool nl = (t < T - 1);
        PHASE(0, 0, STG_A(s + 1, 0), );
        PHASE(1, 0, STG_A(s + 1, 1), );
        PHASE(2, 0, if (nl) STG_B(s + 2, 0), );
        PHASE(3, 0, if (nl) STG_B(s + 2, 1),
              if (nl) { asm volatile("s_waitcnt vmcnt(4)" ::: "memory"); } else { asm volatile("s_waitcnt vmcnt(0)" ::: "memory"); } __builtin_amdgcn_sched_barrier(0); );
        PHASE(4, 1, if (nl) STG_A(s + 2, 0), );
        PHASE(5, 1, if (nl) STG_A(s + 2, 1), );
        PHASE(6, 1, if (nl) STG_B(s + 3, 0), );
        PHASE(7, 1, if (nl) STG_B(s + 3, 1),
              if (nl) { asm volatile("s_waitcnt vmcnt(4)" ::: "memory"); __builtin_amdgcn_sched_barrier(0); } );
    }

    const int r0 = (lane >> 4) * 4;
    #pragma unroll
    for (int n = 0; n < 4; ++n) {
        int colb = bn + wc * 64 + n * 16;
        float bv = bias[colb + fr];
        #pragma unroll
        for (int m = 0; m < 8; ++m) {
            int rowb = bm + wr * 128 + m * 16 + r0;
            if (EPI == 3) {
                unsigned short* qkvB = (unsigned short*)Cout;
                int which = colb >> 10, hh = (colb & 1023) >> 6, dbase = colb & 63;
                int b_ = rowb >> 11, s_ = rowb & 2047;
                long bh2 = b_ * 16 + hh;
                float v[4];
                #pragma unroll
                for (int r = 0; r < 4; ++r) v[r] = acc[m][n][r] + bv;
                if (which == 2) {
                    ushort4v pk;
                    #pragma unroll
                    for (int r = 0; r < 4; ++r) pk[r] = f2bs(v[r]);
                    *(ushort4v*)&qkvB[8388608L + (bh2 * 64 + dbase + fr) * 2048 + s_] = pk;
                } else {
                    unsigned short* dst = qkvB + (long)which * 4194304L +
                                          (bh2 * 2048 + s_) * 64 + dbase + fr;
                    #pragma unroll
                    for (int r = 0; r < 4; ++r) dst[r * 64] = f2bs(v[r]);
                }
            } else {
                #pragma unroll
                for (int r = 0; r < 4; ++r) {
                    long row = rowb + r, col = colb + fr;
                    float v = acc[m][n][r] + bv;
                    v = 0.5f * v * (1.0f + erff(v * 0.70710678118f));
                    ((__hip_bfloat16*)Cout)[row * N + col] = __float2bfloat16(v);
                }
            }
        }
    }
}

template<int EPI>
__global__ __launch_bounds__(512, 1)
void mm_mfma256(const unsigned short* __restrict__ A,
                const unsigned short* __restrict__ BT,
                const float* __restrict__ bias,
                void* __restrict__ Cout, int M, int N, int K, int nbx) {
    extern __shared__ unsigned short LDS[];
    mm256_body<EPI>(LDS, blockIdx.x, gridDim.x, A, BT, bias, Cout, M, N, K, nbx);
}

// 256^2 GEMM (nMM blocks) + convT -> WT2 (remaining blocks), 512 thr
template<int EPI>
__global__ __launch_bounds__(512, 1)
void fused_mm256_convT(const unsigned short* __restrict__ A,
                       const unsigned short* __restrict__ BT,
                       const float* __restrict__ bias,
                       void* __restrict__ Cout, int M, int N, int K, int nbx,
                       const float* __restrict__ W2, unsigned short* __restrict__ WT2,
                       int K2, int N2, int nMM) {
    extern __shared__ unsigned short LDS[];
    int bid = blockIdx.x;
    if (bid < nMM) {
        mm256_body<EPI>(LDS, bid, nMM, A, BT, bias, Cout, M, N, K, nbx);
    } else {
        int r = bid - nMM, kt = K2 >> 6;
        convT_body512((char*)LDS, r % kt, r / kt, W2, WT2, K2, N2);
    }
}

// ---------------- n64 GEMM body (3-buffer, 2-deep prefetch, vmcnt(6)); bf16 residual ----------------
__device__ void n64_body(char* smem, int bx, int by,
                         const unsigned short* __restrict__ A,
                         const unsigned short* __restrict__ BT,
                         const float* __restrict__ bias,
                         const unsigned short* __restrict__ R,
                         unsigned short* __restrict__ Cout, int M, int N, int K) {
    unsigned short* As = (unsigned short*)smem;
    unsigned short* Bs = As + 3 * 128 * 32;
    const int tid = threadIdx.x;
    const int w = tid >> 6, lane = tid & 63;
    const int bm = by * 128, bn = bx * 64;
    const int wr = (w >> 1) * 64, wc = (w & 1) * 32;

    f32x4 acc[4][2];
    #pragma unroll
    for (int m = 0; m < 4; ++m)
        #pragma unroll
        for (int n = 0; n < 2; ++n)
            acc[m][n] = (f32x4){0.f, 0.f, 0.f, 0.f};

    const int lrow = lane >> 2;
    const int lcol = (lane & 3) * 8;
    const unsigned short* gA = A + (long)(bm + w * 32 + lrow) * K + lcol;
    const unsigned short* gB = BT + (long)(bn + w * 16 + lrow) * K + lcol;

#define N64_STAGE(K0, BB) do { \
    gl_lds16(gA + (K0),          &As[(BB) * 4096 + (w * 32) * 32]); \
    gl_lds16(gA + (K0) + 16 * K, &As[(BB) * 4096 + (w * 32 + 16) * 32]); \
    gl_lds16(gB + (K0),          &Bs[(BB) * 2048 + (w * 16) * 32]); \
} while (0)

    const int T = K >> 5;
    N64_STAGE(0, 0);
    if (T > 1) N64_STAGE(32, 1);

    for (int t = 0; t < T; ++t) {
        const int buf = t % 3;
        if (t + 2 < T) {
            N64_STAGE((t + 2) * 32, (t + 2) % 3);
            asm volatile("s_waitcnt vmcnt(6)" ::: "memory");
        } else if (t + 1 < T) {
            asm volatile("s_waitcnt vmcnt(3)" ::: "memory");
        } else {
            asm volatile("s_waitcnt vmcnt(0)" ::: "memory");
        }
        __builtin_amdgcn_sched_barrier(0);
        __builtin_amdgcn_s_barrier();

        bf16x8 a[4], b[2];
        #pragma unroll
        for (int m = 0; m < 4; ++m)
            a[m] = *(const bf16x8*)&As[buf * 4096 + (wr + m * 16 + (lane & 15)) * 32 + (lane >> 4) * 8];
        #pragma unroll
        for (int n = 0; n < 2; ++n)
            b[n] = *(const bf16x8*)&Bs[buf * 2048 + (wc + n * 16 + (lane & 15)) * 32 + (lane >> 4) * 8];
        #pragma unroll
        for (int m = 0; m < 4; ++m)
            #pragma unroll
            for (int n = 0; n < 2; ++n)
                acc[m][n] = __builtin_amdgcn_mfma_f32_16x16x32_bf16(a[m], b[n], acc[m][n], 0, 0, 0);

        __builtin_amdgcn_s_barrier();
    }
#undef N64_STAGE

    const int r0 = (lane >> 4) * 4, cc = lane & 15;
    #pragma unroll
    for (int n = 0; n < 2; ++n) {
        int colb = bn + wc + n * 16;
        float bv = bias[colb + cc];
        #pragma unroll
        for (int m = 0; m < 4; ++m) {
            int rowb = bm + wr + m * 16 + r0;
            #pragma unroll
            for (int r = 0; r < 4; ++r) {
                long row = rowb + r, col = colb + cc;
                float v = acc[m][n][r] + bv + bs2f(R[row * N + col]);
                Cout[row * N + col] = f2bs(v);
            }
        }
    }
}

// ---------------- MFMA flash attention body, QBLK=128, KVBLK=128, 8 waves ----------------
// K double-buffered + counted vmcnt: smem KB[2][128][64] 32K | Vs[64][128] 16K | Ps 32K = 80K
__device__ void attn_body(char* smem, int bh, int qb,
                          const unsigned short* __restrict__ qB,
                          const unsigned short* __restrict__ kB,
                          const unsigned short* __restrict__ vT,
                          __hip_bfloat16* __restrict__ z) {
    const int tid = threadIdx.x, w = tid >> 6, lane = tid & 63;
    const int arow = lane & 15, kg = lane >> 4;
    unsigned short* KB0 = (unsigned short*)smem;
    unsigned short* KB1 = KB0 + 128 * 64;
    unsigned short* Vs  = KB1 + 128 * 64;
    unsigned short* Ps  = Vs + 64 * 128 + w * 16 * 128;

    const long kvbase = (long)bh * (2048 * 64);

    bf16x8 qa[2];
    {
        const unsigned short* q0 = qB + kvbase + (long)(qb + w * 16 + arow) * 64 + kg * 8;
        qa[0] = *(const bf16x8*)(q0);
        qa[1] = *(const bf16x8*)(q0 + 32);
    }

    f32x4 po[4];
    float mrow[4], lrow[4];
    #pragma unroll
    for (int i = 0; i < 4; ++i) {
        po[i] = (f32x4){0.f, 0.f, 0.f, 0.f};
        mrow[i] = -1e30f; lrow[i] = 0.f;
    }

    const int ksrow = lane >> 3;
    const int kschunk = (lane & 7) ^ ksrow;
    const int vsr = lane >> 4;
    const int cmax = qb >> 7;

    const unsigned short* kSrc = kB + kvbase + (long)(w * 16 + ksrow) * 64 + kschunk * 8;

#define STAGE_K(c, KBp) do { \
    gl_lds16(kSrc + (long)(c) * 128 * 64,          &(KBp)[(w * 16) * 64]); \
    gl_lds16(kSrc + (long)(c) * 128 * 64 + 8 * 64, &(KBp)[(w * 16 + 8) * 64]); \
} while (0)
#define STAGE_V(c) do { \
    _Pragma("unroll") \
    for (int i_ = 0; i_ < 2; ++i_) { \
        int d_ = w * 8 + i_ * 4 + vsr; \
        int sch_ = (lane & 15) ^ (d_ & 7); \
        gl_lds16(vT + kvbase + (long)d_ * 2048 + (c) * 128 + sch_ * 8, \
                 &Vs[(w * 8 + i_ * 4) * 128]); \
    } \
} while (0)

    STAGE_K(0, KB0);
    STAGE_V(0);

    for (int c = 0; c <= cmax; ++c) {
        unsigned short* KBcur = (c & 1) ? KB1 : KB0;
        if (c < cmax) {
            STAGE_K(c + 1, (c & 1) ? KB0 : KB1);
            asm volatile("s_waitcnt vmcnt(2)" ::: "memory");
        } else {
            asm volatile("s_waitcnt vmcnt(0)" ::: "memory");
        }
        __builtin_amdgcn_sched_barrier(0);
        __builtin_amdgcn_s_barrier();
        __builtin_amdgcn_sched_barrier(0);

        f32x4 s[8];
        #pragma unroll
        for (int n = 0; n < 8; ++n) {
            s[n] = (f32x4){0.f, 0.f, 0.f, 0.f};
            int row = n * 16 + arow, sw = row & 7;
            bf16x8 kb0 = *(const bf16x8*)&KBcur[row * 64 + (kg ^ sw) * 8];
            bf16x8 kb1 = *(const bf16x8*)&KBcur[row * 64 + ((4 + kg) ^ sw) * 8];
            s[n] = __builtin_amdgcn_mfma_f32_16x16x32_bf16(qa[0], kb0, s[n], 0, 0, 0);
            s[n] = __builtin_amdgcn_mfma_f32_16x16x32_bf16(qa[1], kb1, s[n], 0, 0, 0);
        }

        const bool diag = (c == cmax);
        #pragma unroll
        for (int n = 0; n < 8; ++n)
            #pragma unroll
            for (int r = 0; r < 4; ++r) {
                float v = s[n][r] * 0.125f;
                if (diag) {
                    int key = c * 128 + n * 16 + arow;
                    int qrow = qb + w * 16 + kg * 4 + r;
                    if (key > qrow) v = -1e30f;
                }
                s[n][r] = v;
            }

        #pragma unroll
        for (int r = 0; r < 4; ++r) {
            float rm = s[0][r];
            #pragma unroll
            for (int n = 1; n < 8; ++n) rm = fmaxf(rm, s[n][r]);
            #pragma unroll
            for (int off = 1; off < 16; off <<= 1)
                rm = fmaxf(rm, __shfl_xor(rm, off));
            float mnew = fmaxf(mrow[r], rm);
            float esc = expf(mrow[r] - mnew);
            float rs = 0.f;
            #pragma unroll
            for (int n = 0; n < 8; ++n) {
                float p = expf(s[n][r] - mnew);
                s[n][r] = p;
                rs += p;
            }
            #pragma unroll
            for (int off = 1; off < 16; off <<= 1)
                rs += __shfl_xor(rs, off);
            lrow[r] = lrow[r] * esc + rs;
            #pragma unroll
            for (int dt = 0; dt < 4; ++dt) po[dt][r] *= esc;
            mrow[r] = mnew;
        }

        #pragma unroll
        for (int n = 0; n < 8; ++n) {
            int col = n * 16 + arow;
            int chunk = col >> 3, cw = col & 7;
            #pragma unroll
            for (int r = 0; r < 4; ++r) {
                int row = kg * 4 + r;
                Ps[row * 128 + ((chunk ^ (row & 7)) * 8 + cw)] = f2bs(s[n][r]);
            }
        }

        bf16x8 pa[4];
        #pragma unroll
        for (int ks = 0; ks < 4; ++ks)
            pa[ks] = *(const bf16x8*)&Ps[arow * 128 + (((ks * 4 + kg) ^ (arow & 7)) * 8)];
        #pragma unroll
        for (int dt = 0; dt < 4; ++dt) {
            int vrow = dt * 16 + arow, sw = vrow & 7;
            #pragma unroll
            for (int ks = 0; ks < 4; ++ks) {
                bf16x8 vb = *(const bf16x8*)&Vs[vrow * 128 + (((ks * 4 + kg) ^ sw) * 8)];
                po[dt] = __builtin_amdgcn_mfma_f32_16x16x32_bf16(pa[ks], vb, po[dt], 0, 0, 0);
            }
        }
        __builtin_amdgcn_sched_barrier(0);
        __builtin_amdgcn_s_barrier();
        __builtin_amdgcn_sched_barrier(0);
        if (c < cmax) STAGE_V(c + 1);
    }
#undef STAGE_K
#undef STAGE_V

    const int b_ = bh >> 4, hofs = (bh & 15) * 64;
    #pragma unroll
    for (int dt = 0; dt < 4; ++dt)
        #pragma unroll
        for (int r = 0; r < 4; ++r) {
            long row = (long)b_ * 2048 + qb + w * 16 + kg * 4 + r;
            z[row * 1024 + hofs + dt * 16 + arow] = __float2bfloat16(po[dt][r] / lrow[r]);
        }
}

// ---------------- fused kernels ----------------
__global__ __launch_bounds__(256)
void fused_embed_convT(const int* __restrict__ x, const float* __restrict__ wte,
                       const float* __restrict__ wpe, unsigned short* __restrict__ h,
                       const float* __restrict__ W, unsigned short* __restrict__ WT,
                       int K, int N, int nEmb) {
    extern __shared__ char smem[];
    int bid = blockIdx.x;
    if (bid < nEmb) {
        embed_body(bid, x, wte, wpe, h);
    } else {
        int r = bid - nEmb, kt = K >> 6;
        convT_body(smem, r % kt, r / kt, W, WT, K, N);
    }
}

// attn QBLK=128 heavy-first (nAttn) + convT -> WT2; 512 thr
__global__ __launch_bounds__(512)
void fused_attn_convT(const unsigned short* __restrict__ qB,
                      const unsigned short* __restrict__ kB,
                      const unsigned short* __restrict__ vT,
                      __hip_bfloat16* __restrict__ z,
                      const float* __restrict__ W2, unsigned short* __restrict__ WT2,
                      int K2, int N2, int nAttn) {
    extern __shared__ char smem[];
    int bid = blockIdx.x;
    if (bid < nAttn) {
        int bh = bid & 31;
        int qblk = 15 - (bid >> 5);           // heavy-first
        attn_body(smem, bh, qblk * 128, qB, kB, vT, z);
    } else {
        int r = bid - nAttn, kt = K2 >> 6;
        convT_body512(smem, r % kt, r / kt, W2, WT2, K2, N2);
    }
}

// n64 GEMM (nMM, bx=bid%nbx) + optional convT -> WT2 (nConv blocks)
__global__ __launch_bounds__(256)
void fused_n64_convT(const unsigned short* __restrict__ A,
                     const unsigned short* __restrict__ BT,
                     const float* __restrict__ bias, const unsigned short* __restrict__ R,
                     unsigned short* __restrict__ Cout, int M, int N, int K, int nbx,
                     const float* __restrict__ W2, unsigned short* __restrict__ WT2,
                     int K2, int N2, int nMM) {
    extern __shared__ char smem[];
    int bid = blockIdx.x;
    if (bid < nMM) {
        n64_body(smem, bid % nbx, bid / nbx, A, BT, bias, R, Cout, M, N, K);
    } else {
        int r = bid - nMM, kt = K2 >> 6;
        convT_body(smem, r % kt, r / kt, W2, WT2, K2, N2);
    }
}

// ---------------- head ----------------
__global__ void head_kernel(const float* __restrict__ hl, const float* __restrict__ W,
                            float* __restrict__ out) {
    __shared__ float hs[2 * DMODEL];
    int tid = threadIdx.x;
    #pragma unroll
    for (int i = 0; i < 8; ++i) hs[tid + i * 256] = hl[tid + i * 256];
    __syncthreads();
    int v = blockIdx.x * 256 + tid;
    if (v >= VOCAB) return;
    float a0 = 0.f, a1 = 0.f;
    for (int d = 0; d < DMODEL; ++d) {
        float wv = W[(long)d * VOCAB + v];
        a0 += hs[d] * wv;
        a1 += hs[DMODEL + d] * wv;
    }
    out[v] = a0;
    out[VOCAB + v] = a1;
}

extern "C" void kernel_launch(void* const* d_in, const int* in_sizes, int n_in,
                              void* d_out, int out_size, void* d_ws, size_t ws_size,
                              hipStream_t stream) {
    const int*   x      = (const int*)  d_in[0];
    const float* wte    = (const float*)d_in[1];
    const float* wpe    = (const float*)d_in[2];
    const float* ln1_g  = (const float*)d_in[3];
    const float* ln1_b  = (const float*)d_in[4];
    const float* w_qkv  = (const float*)d_in[5];
    const float* b_qkv  = (const float*)d_in[6];
    const float* w_proj = (const float*)d_in[7];
    const float* b_proj = (const float*)d_in[8];
    const float* ln2_g  = (const float*)d_in[9];
    const float* ln2_b  = (const float*)d_in[10];
    const float* w_fc   = (const float*)d_in[11];
    const float* b_fc   = (const float*)d_in[12];
    const float* w_cp   = (const float*)d_in[13];
    const float* b_cp   = (const float*)d_in[14];
    const float* lnf_g  = (const float*)d_in[15];
    const float* lnf_b  = (const float*)d_in[16];
    const float* w_head = (const float*)d_in[17];
    float* out = (float*)d_out;

    char* ws = (char*)d_ws;
    unsigned short* h     = (unsigned short*)ws;                    // 8 MB (bf16)
    unsigned short* qkvB  = (unsigned short*)(ws + (8L << 20));     // 24 MB
    unsigned short* y_bf  = (unsigned short*)(ws + (32L << 20));    // 8 MB
    __hip_bfloat16* z_bf  = (__hip_bfloat16*)(ws + (40L << 20));    // 8 MB
    unsigned short* fc_bf = (unsigned short*)(ws + (48L << 20));    // 32 MB
    unsigned short* wT_a  = (unsigned short*)(ws + (80L << 20));    // 8 MB (fc)
    unsigned short* wT_b  = (unsigned short*)(ws + (89L << 20));    // 8 MB (proj)
    unsigned short* wT_c  = (unsigned short*)(ws + (98L << 20));    // 8 MB (cp)
    unsigned short* wT_q  = (unsigned short*)(ws + (107L << 20));   // 8 MB (qkv)
    float*          hl    = (float*)(ws + (116L << 20));            // 8 KB

    const int SM_CONV = 16640;   // 64*65*4
    const int SM_ATTN = 81920;   // KB 2x16K + Vs 16K + Ps 32K
    const int SM_N64  = 36864;   // As(24K)+Bs(12K)

    // P: embed (4096) + convT qkv layer 0 (768) -> wT_q
    fused_embed_convT<<<4096 + 768, 256, SM_CONV, stream>>>(
        x, wte, wpe, h, w_qkv, wT_q, 1024, 3072, 4096);

    for (int l = 0; l < NLAYER; ++l) {
        // A: LN1 (wave-per-row, bf16 in/out)
        ln_wave<<<NTOK / 4, 256, 0, stream>>>(h, y_bf, ln1_g + l * DMODEL, ln1_b + l * DMODEL);

        // B: qkv GEMM (192) + convT proj -> wT_b (256)
        fused_mm256_convT<3><<<192 + 256, 512, 131072, stream>>>(
            y_bf, wT_q, b_qkv + l * 3072, qkvB, NTOK, 3072, 1024, 12,
            w_proj + (long)l * DMODEL * DMODEL, wT_b, 1024, 1024, 192);

        // C: attn QBLK=128 (512) + convT cp -> wT_c (1024)
        fused_attn_convT<<<512 + 1024, 512, SM_ATTN, stream>>>(
            qkvB, qkvB + 4194304L, qkvB + 8388608L, z_bf,
            w_cp + (long)l * 4096 * DMODEL, wT_c, 4096, 1024, 512);

        // D: proj GEMM (+bf16 residual) + convT fc -> wT_a (1024)
        fused_n64_convT<<<512 + 1024, 256, SM_N64, stream>>>(
            (const unsigned short*)z_bf, wT_b, b_proj + l * DMODEL, h, h,
            NTOK, 1024, 1024, 16,
            w_fc + (long)l * DMODEL * 4096, wT_a, 1024, 4096, 512);

        // E: LN2 (wave-per-row)
        ln_wave<<<NTOK / 4, 256, 0, stream>>>(h, y_bf, ln2_g + l * DMODEL, ln2_b + l * DMODEL);

        // F: fc GEMM (256^2 8-phase, gelu; reads wT_a)
        mm_mfma256<2><<<256, 512, 131072, stream>>>(
            y_bf, wT_a, b_fc + l * 4096, fc_bf, NTOK, 4096, 1024, 16);

        // G: cp GEMM (+bf16 residual) + convT qkv(l+1) -> wT_q (768; none on last layer)
        int nConv = (l + 1 < NLAYER) ? 768 : 0;
        fused_n64_convT<<<512 + nConv, 256, SM_N64, stream>>>(
            fc_bf, wT_c, b_cp + l * DMODEL, h, h, NTOK, 1024, 4096, 16,
            w_qkv + (long)(l + 1) * DMODEL * 3072, wT_q, 1024, 3072, 512);
    }

    ln_final<<<BATCH, 256, 0, stream>>>(h + (long)(SEQ - 1) * DMODEL, hl,
                                        lnf_g, lnf_b, (long)SEQ * DMODEL);
    head_kernel<<<(VOCAB + 255) / 256, 256, 0, stream>>>(hl, w_head, out);
}